// Round 19
// baseline (331.845 us; speedup 1.0000x reference)
//
#include <hip/hip_runtime.h>
#include <math.h>

#define B_ 32
#define T_ 1024
#define C_ 768
#define M_ (B_ * T_)   // 32768

typedef __attribute__((ext_vector_type(8))) short bf16x8;
typedef __attribute__((ext_vector_type(4))) float f32x4;
typedef __attribute__((ext_vector_type(8))) unsigned short u16x8;
typedef __attribute__((address_space(1))) const void g_void;
typedef __attribute__((address_space(3))) void lds_void;

__device__ __forceinline__ unsigned short f2bf(float f) {
  union { float f; unsigned int u; } v; v.f = f;
  unsigned int u = v.u;
  u += 0x7fffu + ((u >> 16) & 1u);   // RNE
  return (unsigned short)(u >> 16);
}
__device__ __forceinline__ float blo(unsigned int p) {   // low bf16 of packed pair
  union { unsigned int u; float f; } v; v.u = p << 16;
  return v.f;
}
__device__ __forceinline__ float bhi(unsigned int p) {   // high bf16 of packed pair
  union { unsigned int u; float f; } v; v.u = p & 0xffff0000u;
  return v.f;
}

// ---------------------------------------------------------------------------
// prep: fused {4x weight f32->bf16 convert} + {time-shift mix x->xk,xv,xr}
// (round-12 proven)
// ---------------------------------------------------------------------------
#define WPB 288                      // blocks per weight matrix
#define WBLK (4 * WPB)               // 1152
#define MBLK ((M_ * C_ / 8) / 256)   // 12288

__global__ __launch_bounds__(256) void prep(const float* __restrict__ x,
                                            const float* __restrict__ tmk,
                                            const float* __restrict__ tmv,
                                            const float* __restrict__ tmr,
                                            const float* __restrict__ Wk,
                                            const float* __restrict__ Wv,
                                            const float* __restrict__ Wr,
                                            const float* __restrict__ Wo,
                                            unsigned short* __restrict__ wbk,
                                            unsigned short* __restrict__ wbv,
                                            unsigned short* __restrict__ wbr,
                                            unsigned short* __restrict__ wbo,
                                            unsigned short* __restrict__ ok,
                                            unsigned short* __restrict__ ov,
                                            unsigned short* __restrict__ orr) {
  if (blockIdx.x < WBLK) {
    const int sel = blockIdx.x / WPB;              // 0..3
    const int wi = blockIdx.x % WPB;
    const float* src = (sel == 0) ? Wk : (sel == 1) ? Wv : (sel == 2) ? Wr : Wo;
    unsigned short* dst = (sel == 0) ? wbk : (sel == 1) ? wbv : (sel == 2) ? wbr : wbo;
    const int gi = wi * 256 + threadIdx.x;
    const float* p = src + (size_t)gi * 8;
    float v[8];
    *(float4*)&v[0] = *(const float4*)p;
    *(float4*)&v[4] = *(const float4*)(p + 4);
    u16x8 o;
#pragma unroll
    for (int i = 0; i < 8; ++i) o[i] = f2bf(v[i]);
    *(u16x8*)(dst + (size_t)gi * 8) = o;
    return;
  }

  const unsigned int gi = (blockIdx.x - WBLK) * 256u + threadIdx.x;
  const int m = gi / (C_ / 8);
  const int c8 = (gi % (C_ / 8)) * 8;
  const float* xp = x + (size_t)m * C_ + c8;
  float xv8[8], xx8[8], t8[8];
  *(float4*)&xv8[0] = *(const float4*)xp;
  *(float4*)&xv8[4] = *(const float4*)(xp + 4);
  if ((m & (T_ - 1)) != 0) {
    *(float4*)&xx8[0] = *(const float4*)(xp - C_);
    *(float4*)&xx8[4] = *(const float4*)(xp - C_ + 4);
  } else {
#pragma unroll
    for (int i = 0; i < 8; ++i) xx8[i] = 0.f;
  }
  const size_t ob = (size_t)m * C_ + c8;

  *(float4*)&t8[0] = *(const float4*)(tmk + c8);
  *(float4*)&t8[4] = *(const float4*)(tmk + c8 + 4);
  u16x8 o;
#pragma unroll
  for (int i = 0; i < 8; ++i) o[i] = f2bf(xv8[i] * t8[i] + xx8[i] * (1.f - t8[i]));
  *(u16x8*)(ok + ob) = o;

  *(float4*)&t8[0] = *(const float4*)(tmv + c8);
  *(float4*)&t8[4] = *(const float4*)(tmv + c8 + 4);
#pragma unroll
  for (int i = 0; i < 8; ++i) o[i] = f2bf(xv8[i] * t8[i] + xx8[i] * (1.f - t8[i]));
  *(u16x8*)(ov + ob) = o;

  *(float4*)&t8[0] = *(const float4*)(tmr + c8);
  *(float4*)&t8[4] = *(const float4*)(tmr + c8 + 4);
#pragma unroll
  for (int i = 0; i < 8; ++i) o[i] = f2bf(xv8[i] * t8[i] + xx8[i] * (1.f - t8[i]));
  *(u16x8*)(orr + ob) = o;
}

// ---------------------------------------------------------------------------
// Pipelined bf16 GEMM (round-15 proven): BM=128 x BN=128, BK=64, 4 waves,
// double-buffered LDS (64 KiB -> 2 blocks/CU), counted vmcnt 8/0,
// raw s_barrier, XOR swizzle both sides, setprio around MFMA.
// ---------------------------------------------------------------------------
#define GBM 128
#define GBN 128
#define GBK 64
#define GNB ((M_ / GBM) * (C_ / GBN))  // 1536
#define NT (C_ / GBK)                  // 12
#define BUFSZ 16384
#define BOFF_B 8192

#define WAITV(n) asm volatile("s_waitcnt vmcnt(" #n ")" ::: "memory")

template <int OUT_BF16>
__global__ __launch_bounds__(256) void gemm8(const unsigned short* __restrict__ A,
                                             const unsigned short* __restrict__ W,
                                             void* __restrict__ outv) {
  __shared__ unsigned short lds[2 * BUFSZ];

  int bid = (int)blockIdx.x;
  bid = (bid & 7) * (GNB / 8) + (bid >> 3);
  const int mt = bid / (C_ / GBN);
  const int nt = bid % (C_ / GBN);
  const int m0 = mt * GBM, n0 = nt * GBN;

  const int tid = threadIdx.x;
  const int lane = tid & 63;
  const int wv = tid >> 6;
  const int wm = wv >> 1;
  const int wn = wv & 1;

  const int l3 = lane >> 3;
  const int scol = (((lane & 7) ^ l3) << 3);
  const unsigned short* abase = A + (size_t)(m0 + wv * 8 + l3) * C_ + scol;
  const unsigned short* wbase = W + (size_t)(n0 + wv * 8 + l3) * C_ + scol;

#define STAGE(tt, bi)                                                         \
  {                                                                           \
    const int kk0_ = (tt) * GBK;                                              \
    _Pragma("unroll") for (int s_ = 0; s_ < 4; ++s_)                          \
        __builtin_amdgcn_global_load_lds(                                     \
            (g_void*)(abase + (size_t)s_ * 32 * C_ + kk0_),                   \
            (lds_void*)&lds[(bi) * BUFSZ + s_ * 2048 + wv * 512], 16, 0, 0);  \
    _Pragma("unroll") for (int s_ = 0; s_ < 4; ++s_)                          \
        __builtin_amdgcn_global_load_lds(                                     \
            (g_void*)(wbase + (size_t)s_ * 32 * C_ + kk0_),                   \
            (lds_void*)&lds[(bi) * BUFSZ + BOFF_B + s_ * 2048 + wv * 512],    \
            16, 0, 0);                                                        \
  }

  STAGE(0, 0);
  STAGE(1, 1);

  f32x4 acc[4][4] = {};
  const int arow = wm * 64 + (lane & 15);
  const int brow = wn * 64 + (lane & 15);

  for (int t = 0; t < NT; ++t) {
    if (t < NT - 1) { WAITV(8); }
    else { WAITV(0); }
    __builtin_amdgcn_s_barrier();
    __builtin_amdgcn_sched_barrier(0);

    const unsigned short* bufA = &lds[(t & 1) * BUFSZ];
    const unsigned short* bufB = bufA + BOFF_B;

#pragma unroll
    for (int kk = 0; kk < 2; ++kk) {
      const int sw = ((((kk << 2) | (lane >> 4)) ^ (lane & 7)) << 3);
      bf16x8 af[4], bfv[4];
#pragma unroll
      for (int f = 0; f < 4; ++f)
        af[f] = *(const bf16x8*)&bufA[(arow + f * 16) * 64 + sw];
#pragma unroll
      for (int f = 0; f < 4; ++f)
        bfv[f] = *(const bf16x8*)&bufB[(brow + f * 16) * 64 + sw];
      __builtin_amdgcn_s_setprio(1);
#pragma unroll
      for (int i = 0; i < 4; ++i)
#pragma unroll
        for (int j = 0; j < 4; ++j)
          acc[i][j] = __builtin_amdgcn_mfma_f32_16x16x32_bf16(af[i], bfv[j], acc[i][j], 0, 0, 0);
      __builtin_amdgcn_s_setprio(0);
    }

    __builtin_amdgcn_s_barrier();
    __builtin_amdgcn_sched_barrier(0);
    if (t + 2 < NT) STAGE(t + 2, t & 1);
  }

  const int crow0 = m0 + wm * 64 + (lane >> 4) * 4;
  const int ccol0 = n0 + wn * 64 + (lane & 15);
  if (OUT_BF16) {
    unsigned short* out = (unsigned short*)outv;
#pragma unroll
    for (int i = 0; i < 4; ++i)
#pragma unroll
      for (int j = 0; j < 4; ++j)
#pragma unroll
        for (int r = 0; r < 4; ++r)
          out[(size_t)(crow0 + i * 16 + r) * C_ + ccol0 + j * 16] = f2bf(acc[i][j][r]);
  } else {
    float* out = (float*)outv;
#pragma unroll
    for (int i = 0; i < 4; ++i)
#pragma unroll
      for (int j = 0; j < 4; ++j)
#pragma unroll
        for (int r = 0; r < 4; ++r)
          out[(size_t)(crow0 + i * 16 + r) * C_ + ccol0 + j * 16] = acc[i][j][r];
  }
#undef STAGE
}

// ---------------------------------------------------------------------------
// WKV chunked associative scan -- round-19: 512 threads, 64 ch/block
// (128B wave segments, r13-proven), FOUR chunks per thread (j, j+16,
// j+32, j+48): 8 independent scan chains/thread -> 8-way ILP on the
// exp-latency chain; serial chain per phase drops to CL=16.
// Math: r16's cndmask exp form (r18's dual-exp was trans-contended).
// ---------------------------------------------------------------------------
#define NCH 64
#define CL  (T_ / NCH)   // 16

#define SCAN_STEP(w_, kt, vt, p_, q_, o_)                    \
  {                                                          \
    const float d_ = (w_ + o_) - (kt);                       \
    const float e_ = __expf(-fabsf(d_));                     \
    const float A_ = (d_ < 0.f) ? e_ : 1.f;                  \
    const float Bc_ = (d_ < 0.f) ? 1.f : e_;                 \
    p_ = A_ * p_ + Bc_ * (vt);                               \
    q_ = A_ * q_ + Bc_;                                      \
    o_ = fmaxf(w_ + o_, (kt));                               \
  }

#define KS_COMBINE(w_, lp_, lq_, lo_, p_, q_, o_, span_)     \
  {                                                          \
    const float dsp_ = (w_) * (float)(span_) + (lo_);        \
    const float dd_ = dsp_ - o_;                             \
    const float e_ = __expf(-fabsf(dd_));                    \
    const float ea_ = (dd_ < 0.f) ? e_ : 1.f;                \
    const float eb_ = (dd_ < 0.f) ? 1.f : e_;                \
    p_ = ea_ * (lp_) + eb_ * p_;                             \
    q_ = ea_ * (lq_) + eb_ * q_;                             \
    o_ = fmaxf(dsp_, o_);                                    \
  }

#define Y_STEP(w_, u_, kt, vt, rt, pp_, qq_, oo_, zres_)     \
  {                                                          \
    const float d1_ = oo_ - ((u_) + (kt));                   \
    const float e1_ = __expf(-fabsf(d1_));                   \
    const float Ae_ = (d1_ < 0.f) ? e1_ : 1.f;               \
    const float Be_ = (d1_ < 0.f) ? 1.f : e1_;               \
    const float er_ = __expf(-(rt));                         \
    zres_ = __fdividef(Ae_ * pp_ + Be_ * (vt),               \
                       (Ae_ * qq_ + Be_) * (1.f + er_));     \
    SCAN_STEP(w_, kt, vt, pp_, qq_, oo_)                     \
  }

// per-chunk state bundle helpers (index X in {A,B,C,D} -> chunk j + 16*X)
#define LOAD_KV(X, idx)                                               \
  const unsigned int k##X = *(const unsigned int*)(kin + (idx));      \
  const unsigned int v##X = *(const unsigned int*)(vin + (idx));

#define STORE_STATE(jj, p0_, q0_, o0_, p1_, q1_, o1_)                 \
  ps[jj][2 * ci] = p0_; qs[jj][2 * ci] = q0_; os[jj][2 * ci] = o0_;   \
  ps[jj][2 * ci + 1] = p1_; qs[jj][2 * ci + 1] = q1_; os[jj][2 * ci + 1] = o1_;

__global__ __launch_bounds__(512) void wkv_scan(const unsigned short* __restrict__ kin,
                                                const unsigned short* __restrict__ vin,
                                                const unsigned short* __restrict__ rin,
                                                const float* __restrict__ wdec,
                                                const float* __restrict__ ufirst,
                                                unsigned short* __restrict__ z) {
  __shared__ float ps[NCH][64], qs[NCH][64], os[NCH][64];   // 48 KB

  const int b = blockIdx.x / (C_ / 64);
  const int cg = blockIdx.x % (C_ / 64);
  const int ci = threadIdx.x & 31;           // channel-pair index 0..31
  const int j = threadIdx.x >> 5;            // 0..15
  const int jA = j, jB = j + 16, jC = j + 32, jD = j + 48;
  const int c0 = cg * 64 + 2 * ci;
  const float w0 = wdec[c0], w1 = wdec[c0 + 1];
  const float u0 = ufirst[c0], u1 = ufirst[c0 + 1];
  const size_t baseA = ((size_t)b * T_ + (size_t)jA * CL) * C_ + c0;
  const size_t baseB = ((size_t)b * T_ + (size_t)jB * CL) * C_ + c0;
  const size_t baseC = ((size_t)b * T_ + (size_t)jC * CL) * C_ + c0;
  const size_t baseD = ((size_t)b * T_ + (size_t)jD * CL) * C_ + c0;

  // ---- phase 1: four independent local chunk scans (8 chains) ----
  float Ap0 = 0.f, Aq0 = 0.f, Ao0 = -1e38f, Ap1 = 0.f, Aq1 = 0.f, Ao1 = -1e38f;
  float Bp0 = 0.f, Bq0 = 0.f, Bo0 = -1e38f, Bp1 = 0.f, Bq1 = 0.f, Bo1 = -1e38f;
  float Cp0 = 0.f, Cq0 = 0.f, Co0 = -1e38f, Cp1 = 0.f, Cq1 = 0.f, Co1 = -1e38f;
  float Dp0 = 0.f, Dq0 = 0.f, Do0 = -1e38f, Dp1 = 0.f, Dq1 = 0.f, Do1 = -1e38f;
  {
    size_t ia = baseA, ib = baseB, ic = baseC, id = baseD;
#pragma unroll 2
    for (int t = 0; t < CL; ++t, ia += C_, ib += C_, ic += C_, id += C_) {
      LOAD_KV(A, ia) LOAD_KV(B, ib) LOAD_KV(C, ic) LOAD_KV(D, id)
      SCAN_STEP(w0, blo(kA), blo(vA), Ap0, Aq0, Ao0)
      SCAN_STEP(w1, bhi(kA), bhi(vA), Ap1, Aq1, Ao1)
      SCAN_STEP(w0, blo(kB), blo(vB), Bp0, Bq0, Bo0)
      SCAN_STEP(w1, bhi(kB), bhi(vB), Bp1, Bq1, Bo1)
      SCAN_STEP(w0, blo(kC), blo(vC), Cp0, Cq0, Co0)
      SCAN_STEP(w1, bhi(kC), bhi(vC), Cp1, Cq1, Co1)
      SCAN_STEP(w0, blo(kD), blo(vD), Dp0, Dq0, Do0)
      SCAN_STEP(w1, bhi(kD), bhi(vD), Dp1, Dq1, Do1)
    }
  }
  STORE_STATE(jA, Ap0, Aq0, Ao0, Ap1, Aq1, Ao1)
  STORE_STATE(jB, Bp0, Bq0, Bo0, Bp1, Bq1, Bo1)
  STORE_STATE(jC, Cp0, Cq0, Co0, Cp1, Cq1, Co1)
  STORE_STATE(jD, Dp0, Dq0, Do0, Dp1, Dq1, Do1)
  __syncthreads();

  // ---- phase 2: Kogge-Stone over 64 chunks (6 steps) ----
#pragma unroll
  for (int s = 1; s < NCH; s <<= 1) {
    float tA0 = Ap0, tA1 = Aq0, tA2 = Ao0, tA3 = Ap1, tA4 = Aq1, tA5 = Ao1;
    float tB0 = Bp0, tB1 = Bq0, tB2 = Bo0, tB3 = Bp1, tB4 = Bq1, tB5 = Bo1;
    float tC0 = Cp0, tC1 = Cq0, tC2 = Co0, tC3 = Cp1, tC4 = Cq1, tC5 = Co1;
    float tD0 = Dp0, tD1 = Dq0, tD2 = Do0, tD3 = Dp1, tD4 = Dq1, tD5 = Do1;
    if (jA >= s) {   // false for s>=16 (j<16): compile-time prunes
      KS_COMBINE(w0, ps[jA - s][2 * ci], qs[jA - s][2 * ci], os[jA - s][2 * ci],
                 tA0, tA1, tA2, s * CL)
      KS_COMBINE(w1, ps[jA - s][2 * ci + 1], qs[jA - s][2 * ci + 1], os[jA - s][2 * ci + 1],
                 tA3, tA4, tA5, s * CL)
    }
    if (jB >= s) {   // true for s<=16; false at s=32
      KS_COMBINE(w0, ps[jB - s][2 * ci], qs[jB - s][2 * ci], os[jB - s][2 * ci],
                 tB0, tB1, tB2, s * CL)
      KS_COMBINE(w1, ps[jB - s][2 * ci + 1], qs[jB - s][2 * ci + 1], os[jB - s][2 * ci + 1],
                 tB3, tB4, tB5, s * CL)
    }
    // jC >= 32 >= s and jD >= 48 >= s always (s <= 32)
    KS_COMBINE(w0, ps[jC - s][2 * ci], qs[jC - s][2 * ci], os[jC - s][2 * ci],
               tC0, tC1, tC2, s * CL)
    KS_COMBINE(w1, ps[jC - s][2 * ci + 1], qs[jC - s][2 * ci + 1], os[jC - s][2 * ci + 1],
               tC3, tC4, tC5, s * CL)
    KS_COMBINE(w0, ps[jD - s][2 * ci], qs[jD - s][2 * ci], os[jD - s][2 * ci],
               tD0, tD1, tD2, s * CL)
    KS_COMBINE(w1, ps[jD - s][2 * ci + 1], qs[jD - s][2 * ci + 1], os[jD - s][2 * ci + 1],
               tD3, tD4, tD5, s * CL)
    __syncthreads();
    Ap0 = tA0; Aq0 = tA1; Ao0 = tA2; Ap1 = tA3; Aq1 = tA4; Ao1 = tA5;
    Bp0 = tB0; Bq0 = tB1; Bo0 = tB2; Bp1 = tB3; Bq1 = tB4; Bo1 = tB5;
    Cp0 = tC0; Cq0 = tC1; Co0 = tC2; Cp1 = tC3; Cq1 = tC4; Co1 = tC5;
    Dp0 = tD0; Dq0 = tD1; Do0 = tD2; Dp1 = tD3; Dq1 = tD4; Do1 = tD5;
    STORE_STATE(jA, Ap0, Aq0, Ao0, Ap1, Aq1, Ao1)
    STORE_STATE(jB, Bp0, Bq0, Bo0, Bp1, Bq1, Bo1)
    STORE_STATE(jC, Cp0, Cq0, Co0, Cp1, Cq1, Co1)
    STORE_STATE(jD, Dp0, Dq0, Do0, Dp1, Dq1, Do1)
    __syncthreads();
  }

  // ---- phase 3: re-scan all four chunks with exclusive prefixes ----
  float pA0 = 0.f, qA0 = 0.f, oA0 = -1e38f, pA1 = 0.f, qA1 = 0.f, oA1 = -1e38f;
  if (j > 0) {
    pA0 = ps[jA - 1][2 * ci]; qA0 = qs[jA - 1][2 * ci]; oA0 = os[jA - 1][2 * ci];
    pA1 = ps[jA - 1][2 * ci + 1]; qA1 = qs[jA - 1][2 * ci + 1]; oA1 = os[jA - 1][2 * ci + 1];
  }
  float pB0 = ps[jB - 1][2 * ci], qB0 = qs[jB - 1][2 * ci], oB0 = os[jB - 1][2 * ci];
  float pB1 = ps[jB - 1][2 * ci + 1], qB1 = qs[jB - 1][2 * ci + 1], oB1 = os[jB - 1][2 * ci + 1];
  float pC0 = ps[jC - 1][2 * ci], qC0 = qs[jC - 1][2 * ci], oC0 = os[jC - 1][2 * ci];
  float pC1 = ps[jC - 1][2 * ci + 1], qC1 = qs[jC - 1][2 * ci + 1], oC1 = os[jC - 1][2 * ci + 1];
  float pD0 = ps[jD - 1][2 * ci], qD0 = qs[jD - 1][2 * ci], oD0 = os[jD - 1][2 * ci];
  float pD1 = ps[jD - 1][2 * ci + 1], qD1 = qs[jD - 1][2 * ci + 1], oD1 = os[jD - 1][2 * ci + 1];

  {
    size_t ia = baseA, ib = baseB, ic = baseC, id = baseD;
#pragma unroll 2
    for (int t = 0; t < CL; ++t, ia += C_, ib += C_, ic += C_, id += C_) {
      LOAD_KV(A, ia) LOAD_KV(B, ib) LOAD_KV(C, ic) LOAD_KV(D, id)
      const unsigned int rA = *(const unsigned int*)(rin + ia);
      const unsigned int rB = *(const unsigned int*)(rin + ib);
      const unsigned int rC = *(const unsigned int*)(rin + ic);
      const unsigned int rD = *(const unsigned int*)(rin + id);
      float y0, y1;
      Y_STEP(w0, u0, blo(kA), blo(vA), blo(rA), pA0, qA0, oA0, y0)
      Y_STEP(w1, u1, bhi(kA), bhi(vA), bhi(rA), pA1, qA1, oA1, y1)
      *(unsigned int*)(z + ia) = (unsigned int)f2bf(y0) | (((unsigned int)f2bf(y1)) << 16);
      Y_STEP(w0, u0, blo(kB), blo(vB), blo(rB), pB0, qB0, oB0, y0)
      Y_STEP(w1, u1, bhi(kB), bhi(vB), bhi(rB), pB1, qB1, oB1, y1)
      *(unsigned int*)(z + ib) = (unsigned int)f2bf(y0) | (((unsigned int)f2bf(y1)) << 16);
      Y_STEP(w0, u0, blo(kC), blo(vC), blo(rC), pC0, qC0, oC0, y0)
      Y_STEP(w1, u1, bhi(kC), bhi(vC), bhi(rC), pC1, qC1, oC1, y1)
      *(unsigned int*)(z + ic) = (unsigned int)f2bf(y0) | (((unsigned int)f2bf(y1)) << 16);
      Y_STEP(w0, u0, blo(kD), blo(vD), blo(rD), pD0, qD0, oD0, y0)
      Y_STEP(w1, u1, bhi(kD), bhi(vD), bhi(rD), pD1, qD1, oD1, y1)
      *(unsigned int*)(z + id) = (unsigned int)f2bf(y0) | (((unsigned int)f2bf(y1)) << 16);
    }
  }
}

// ---------------------------------------------------------------------------
extern "C" void kernel_launch(void* const* d_in, const int* in_sizes, int n_in,
                              void* d_out, int out_size, void* d_ws,
                              size_t ws_size, hipStream_t stream) {
  const float* x   = (const float*)d_in[0];
  const float* td  = (const float*)d_in[1];
  const float* tf  = (const float*)d_in[2];
  const float* tmk = (const float*)d_in[3];
  const float* tmv = (const float*)d_in[4];
  const float* tmr = (const float*)d_in[5];
  const float* Wk  = (const float*)d_in[6];
  const float* Wv  = (const float*)d_in[7];
  const float* Wr  = (const float*)d_in[8];
  const float* Wo  = (const float*)d_in[9];

  const size_t nW = (size_t)C_ * C_;
  const size_t nM = (size_t)M_ * C_;

  // ws (244.5 MiB): [wbk wbv wbr wbo][xk][xv][xr][kbuf][vbuf]  (all bf16)
  // rbuf lives in d_out (bf16; consumed by wkv before final GEMM overwrites)
  // z overlays xv (dead after gemm_v)
  unsigned short* wbk  = (unsigned short*)d_ws;
  unsigned short* wbv  = wbk + nW;
  unsigned short* wbr  = wbv + nW;
  unsigned short* wbo  = wbr + nW;
  unsigned short* xk   = wbo + nW;
  unsigned short* xv   = xk + nM;
  unsigned short* xr   = xv + nM;
  unsigned short* kbuf = xr + nM;
  unsigned short* vbuf = kbuf + nM;
  unsigned short* rbuf = (unsigned short*)d_out;
  unsigned short* zb   = xv;   // reuse

  prep<<<WBLK + MBLK, 256, 0, stream>>>(x, tmk, tmv, tmr, Wk, Wv, Wr, Wo,
                                        wbk, wbv, wbr, wbo, xk, xv, xr);

  gemm8<1><<<GNB, 256, 0, stream>>>(xk, wbk, kbuf);   // xk dies
  gemm8<1><<<GNB, 256, 0, stream>>>(xv, wbv, vbuf);   // xv dies
  gemm8<1><<<GNB, 256, 0, stream>>>(xr, wbr, rbuf);   // -> d_out (bf16)

  wkv_scan<<<B_ * (C_ / 64), 512, 0, stream>>>(kbuf, vbuf, rbuf, td, tf, zb);

  gemm8<0><<<GNB, 256, 0, stream>>>(zb, wbo, d_out);  // f32 out
}

// Round 20
// 318.869 us; speedup vs baseline: 1.0407x; 1.0407x over previous
//
#include <hip/hip_runtime.h>
#include <math.h>

#define B_ 32
#define T_ 1024
#define C_ 768
#define M_ (B_ * T_)   // 32768

typedef __attribute__((ext_vector_type(8))) short bf16x8;
typedef __attribute__((ext_vector_type(4))) float f32x4;
typedef __attribute__((ext_vector_type(8))) unsigned short u16x8;
typedef __attribute__((address_space(1))) const void g_void;
typedef __attribute__((address_space(3))) void lds_void;

__device__ __forceinline__ unsigned short f2bf(float f) {
  union { float f; unsigned int u; } v; v.f = f;
  unsigned int u = v.u;
  u += 0x7fffu + ((u >> 16) & 1u);   // RNE
  return (unsigned short)(u >> 16);
}
__device__ __forceinline__ float blo(unsigned int p) {   // low bf16 of packed pair
  union { unsigned int u; float f; } v; v.u = p << 16;
  return v.f;
}
__device__ __forceinline__ float bhi(unsigned int p) {   // high bf16 of packed pair
  union { unsigned int u; float f; } v; v.u = p & 0xffff0000u;
  return v.f;
}

// ---------------------------------------------------------------------------
// prep: fused {4x weight f32->bf16 convert} + {time-shift mix x->xk,xv,xr}
// (round-12 proven; ~40 us at ~75% HBM BW -- near floor)
// ---------------------------------------------------------------------------
#define WPB 288                      // blocks per weight matrix
#define WBLK (4 * WPB)               // 1152
#define MBLK ((M_ * C_ / 8) / 256)   // 12288

__global__ __launch_bounds__(256) void prep(const float* __restrict__ x,
                                            const float* __restrict__ tmk,
                                            const float* __restrict__ tmv,
                                            const float* __restrict__ tmr,
                                            const float* __restrict__ Wk,
                                            const float* __restrict__ Wv,
                                            const float* __restrict__ Wr,
                                            const float* __restrict__ Wo,
                                            unsigned short* __restrict__ wbk,
                                            unsigned short* __restrict__ wbv,
                                            unsigned short* __restrict__ wbr,
                                            unsigned short* __restrict__ wbo,
                                            unsigned short* __restrict__ ok,
                                            unsigned short* __restrict__ ov,
                                            unsigned short* __restrict__ orr) {
  if (blockIdx.x < WBLK) {
    const int sel = blockIdx.x / WPB;              // 0..3
    const int wi = blockIdx.x % WPB;
    const float* src = (sel == 0) ? Wk : (sel == 1) ? Wv : (sel == 2) ? Wr : Wo;
    unsigned short* dst = (sel == 0) ? wbk : (sel == 1) ? wbv : (sel == 2) ? wbr : wbo;
    const int gi = wi * 256 + threadIdx.x;
    const float* p = src + (size_t)gi * 8;
    float v[8];
    *(float4*)&v[0] = *(const float4*)p;
    *(float4*)&v[4] = *(const float4*)(p + 4);
    u16x8 o;
#pragma unroll
    for (int i = 0; i < 8; ++i) o[i] = f2bf(v[i]);
    *(u16x8*)(dst + (size_t)gi * 8) = o;
    return;
  }

  const unsigned int gi = (blockIdx.x - WBLK) * 256u + threadIdx.x;
  const int m = gi / (C_ / 8);
  const int c8 = (gi % (C_ / 8)) * 8;
  const float* xp = x + (size_t)m * C_ + c8;
  float xv8[8], xx8[8], t8[8];
  *(float4*)&xv8[0] = *(const float4*)xp;
  *(float4*)&xv8[4] = *(const float4*)(xp + 4);
  if ((m & (T_ - 1)) != 0) {
    *(float4*)&xx8[0] = *(const float4*)(xp - C_);
    *(float4*)&xx8[4] = *(const float4*)(xp - C_ + 4);
  } else {
#pragma unroll
    for (int i = 0; i < 8; ++i) xx8[i] = 0.f;
  }
  const size_t ob = (size_t)m * C_ + c8;

  *(float4*)&t8[0] = *(const float4*)(tmk + c8);
  *(float4*)&t8[4] = *(const float4*)(tmk + c8 + 4);
  u16x8 o;
#pragma unroll
  for (int i = 0; i < 8; ++i) o[i] = f2bf(xv8[i] * t8[i] + xx8[i] * (1.f - t8[i]));
  *(u16x8*)(ok + ob) = o;

  *(float4*)&t8[0] = *(const float4*)(tmv + c8);
  *(float4*)&t8[4] = *(const float4*)(tmv + c8 + 4);
#pragma unroll
  for (int i = 0; i < 8; ++i) o[i] = f2bf(xv8[i] * t8[i] + xx8[i] * (1.f - t8[i]));
  *(u16x8*)(ov + ob) = o;

  *(float4*)&t8[0] = *(const float4*)(tmr + c8);
  *(float4*)&t8[4] = *(const float4*)(tmr + c8 + 4);
#pragma unroll
  for (int i = 0; i < 8; ++i) o[i] = f2bf(xv8[i] * t8[i] + xx8[i] * (1.f - t8[i]));
  *(u16x8*)(orr + ob) = o;
}

// ---------------------------------------------------------------------------
// Pipelined bf16 GEMM (round-15 proven; ~47 us ea, 823 TF ~= 90% of the
// 2-barrier-structure ceiling): BM=128 x BN=128, BK=64, 4 waves,
// double-buffered LDS (64 KiB -> 2 blocks/CU), counted vmcnt 8/0,
// raw s_barrier, XOR swizzle both sides, setprio around MFMA.
// ---------------------------------------------------------------------------
#define GBM 128
#define GBN 128
#define GBK 64
#define GNB ((M_ / GBM) * (C_ / GBN))  // 1536
#define NT (C_ / GBK)                  // 12
#define BUFSZ 16384
#define BOFF_B 8192

#define WAITV(n) asm volatile("s_waitcnt vmcnt(" #n ")" ::: "memory")

template <int OUT_BF16>
__global__ __launch_bounds__(256) void gemm8(const unsigned short* __restrict__ A,
                                             const unsigned short* __restrict__ W,
                                             void* __restrict__ outv) {
  __shared__ unsigned short lds[2 * BUFSZ];

  int bid = (int)blockIdx.x;
  bid = (bid & 7) * (GNB / 8) + (bid >> 3);
  const int mt = bid / (C_ / GBN);
  const int nt = bid % (C_ / GBN);
  const int m0 = mt * GBM, n0 = nt * GBN;

  const int tid = threadIdx.x;
  const int lane = tid & 63;
  const int wv = tid >> 6;
  const int wm = wv >> 1;
  const int wn = wv & 1;

  const int l3 = lane >> 3;
  const int scol = (((lane & 7) ^ l3) << 3);
  const unsigned short* abase = A + (size_t)(m0 + wv * 8 + l3) * C_ + scol;
  const unsigned short* wbase = W + (size_t)(n0 + wv * 8 + l3) * C_ + scol;

#define STAGE(tt, bi)                                                         \
  {                                                                           \
    const int kk0_ = (tt) * GBK;                                              \
    _Pragma("unroll") for (int s_ = 0; s_ < 4; ++s_)                          \
        __builtin_amdgcn_global_load_lds(                                     \
            (g_void*)(abase + (size_t)s_ * 32 * C_ + kk0_),                   \
            (lds_void*)&lds[(bi) * BUFSZ + s_ * 2048 + wv * 512], 16, 0, 0);  \
    _Pragma("unroll") for (int s_ = 0; s_ < 4; ++s_)                          \
        __builtin_amdgcn_global_load_lds(                                     \
            (g_void*)(wbase + (size_t)s_ * 32 * C_ + kk0_),                   \
            (lds_void*)&lds[(bi) * BUFSZ + BOFF_B + s_ * 2048 + wv * 512],    \
            16, 0, 0);                                                        \
  }

  STAGE(0, 0);
  STAGE(1, 1);

  f32x4 acc[4][4] = {};
  const int arow = wm * 64 + (lane & 15);
  const int brow = wn * 64 + (lane & 15);

  for (int t = 0; t < NT; ++t) {
    if (t < NT - 1) { WAITV(8); }
    else { WAITV(0); }
    __builtin_amdgcn_s_barrier();
    __builtin_amdgcn_sched_barrier(0);

    const unsigned short* bufA = &lds[(t & 1) * BUFSZ];
    const unsigned short* bufB = bufA + BOFF_B;

#pragma unroll
    for (int kk = 0; kk < 2; ++kk) {
      const int sw = ((((kk << 2) | (lane >> 4)) ^ (lane & 7)) << 3);
      bf16x8 af[4], bfv[4];
#pragma unroll
      for (int f = 0; f < 4; ++f)
        af[f] = *(const bf16x8*)&bufA[(arow + f * 16) * 64 + sw];
#pragma unroll
      for (int f = 0; f < 4; ++f)
        bfv[f] = *(const bf16x8*)&bufB[(brow + f * 16) * 64 + sw];
      __builtin_amdgcn_s_setprio(1);
#pragma unroll
      for (int i = 0; i < 4; ++i)
#pragma unroll
        for (int j = 0; j < 4; ++j)
          acc[i][j] = __builtin_amdgcn_mfma_f32_16x16x32_bf16(af[i], bfv[j], acc[i][j], 0, 0, 0);
      __builtin_amdgcn_s_setprio(0);
    }

    __builtin_amdgcn_s_barrier();
    __builtin_amdgcn_sched_barrier(0);
    if (t + 2 < NT) STAGE(t + 2, t & 1);
  }

  const int crow0 = m0 + wm * 64 + (lane >> 4) * 4;
  const int ccol0 = n0 + wn * 64 + (lane & 15);
  if (OUT_BF16) {
    unsigned short* out = (unsigned short*)outv;
#pragma unroll
    for (int i = 0; i < 4; ++i)
#pragma unroll
      for (int j = 0; j < 4; ++j)
#pragma unroll
        for (int r = 0; r < 4; ++r)
          out[(size_t)(crow0 + i * 16 + r) * C_ + ccol0 + j * 16] = f2bf(acc[i][j][r]);
  } else {
    float* out = (float*)outv;
#pragma unroll
    for (int i = 0; i < 4; ++i)
#pragma unroll
      for (int j = 0; j < 4; ++j)
#pragma unroll
        for (int r = 0; r < 4; ++r)
          out[(size_t)(crow0 + i * 16 + r) * C_ + ccol0 + j * 16] = acc[i][j][r];
  }
#undef STAGE
}

// ---------------------------------------------------------------------------
// WKV chunked associative scan -- round-16 form, the empirical optimum
// (75.7 us): 512 threads, 64 channels/block (packed pairs -> 128B wave
// segments), 2 chunks/thread (jA=j, jB=j+16) for 2-way exp-chain ILP,
// cndmask single-exp math. Tested and worse: reg-cache (spills), 1024-thr
// (fetch x2 at 32ch / LDS-occupancy), 4-chunk (LDS 48KB -> occ 26%),
// dual-exp branchless (trans-contended).
// ---------------------------------------------------------------------------
#define NCH 32
#define CL  (T_ / NCH)   // 32

#define SCAN_STEP(w_, kt, vt, p_, q_, o_)                    \
  {                                                          \
    const float d_ = (w_ + o_) - (kt);                       \
    const float e_ = __expf(-fabsf(d_));                     \
    const float A_ = (d_ < 0.f) ? e_ : 1.f;                  \
    const float Bc_ = (d_ < 0.f) ? 1.f : e_;                 \
    p_ = A_ * p_ + Bc_ * (vt);                               \
    q_ = A_ * q_ + Bc_;                                      \
    o_ = fmaxf(w_ + o_, (kt));                               \
  }

#define KS_COMBINE(w_, lp_, lq_, lo_, p_, q_, o_, span_)     \
  {                                                          \
    const float dsp_ = (w_) * (float)(span_) + (lo_);        \
    const float dd_ = dsp_ - o_;                             \
    const float e_ = __expf(-fabsf(dd_));                    \
    const float ea_ = (dd_ < 0.f) ? e_ : 1.f;                \
    const float eb_ = (dd_ < 0.f) ? 1.f : e_;                \
    p_ = ea_ * (lp_) + eb_ * p_;                             \
    q_ = ea_ * (lq_) + eb_ * q_;                             \
    o_ = fmaxf(dsp_, o_);                                    \
  }

#define Y_STEP(w_, u_, kt, vt, rt, pp_, qq_, oo_, zres_)     \
  {                                                          \
    const float d1_ = oo_ - ((u_) + (kt));                   \
    const float e1_ = __expf(-fabsf(d1_));                   \
    const float Ae_ = (d1_ < 0.f) ? e1_ : 1.f;               \
    const float Be_ = (d1_ < 0.f) ? 1.f : e1_;               \
    const float er_ = __expf(-(rt));                         \
    zres_ = __fdividef(Ae_ * pp_ + Be_ * (vt),               \
                       (Ae_ * qq_ + Be_) * (1.f + er_));     \
    SCAN_STEP(w_, kt, vt, pp_, qq_, oo_)                     \
  }

__global__ __launch_bounds__(512) void wkv_scan(const unsigned short* __restrict__ kin,
                                                const unsigned short* __restrict__ vin,
                                                const unsigned short* __restrict__ rin,
                                                const float* __restrict__ wdec,
                                                const float* __restrict__ ufirst,
                                                unsigned short* __restrict__ z) {
  __shared__ float ps[NCH][64], qs[NCH][64], os[NCH][64];

  const int b = blockIdx.x / (C_ / 64);
  const int cg = blockIdx.x % (C_ / 64);
  const int ci = threadIdx.x & 31;           // channel-pair index 0..31
  const int j = threadIdx.x >> 5;            // 0..15
  const int jA = j, jB = j + 16;             // this thread's two chunks
  const int c0 = cg * 64 + 2 * ci;
  const float w0 = wdec[c0], w1 = wdec[c0 + 1];
  const float u0 = ufirst[c0], u1 = ufirst[c0 + 1];
  const size_t baseA = ((size_t)b * T_ + (size_t)jA * CL) * C_ + c0;
  const size_t baseB = ((size_t)b * T_ + (size_t)jB * CL) * C_ + c0;

  // ---- phase 1: two independent local chunk scans (2-way ILP) ----
  float Ap0 = 0.f, Aq0 = 0.f, Ao0 = -1e38f, Ap1 = 0.f, Aq1 = 0.f, Ao1 = -1e38f;
  float Bp0 = 0.f, Bq0 = 0.f, Bo0 = -1e38f, Bp1 = 0.f, Bq1 = 0.f, Bo1 = -1e38f;
  {
    size_t ia = baseA, ib = baseB;
#pragma unroll 4
    for (int t = 0; t < CL; ++t, ia += C_, ib += C_) {
      const unsigned int kA = *(const unsigned int*)(kin + ia);
      const unsigned int vA = *(const unsigned int*)(vin + ia);
      const unsigned int kB = *(const unsigned int*)(kin + ib);
      const unsigned int vB = *(const unsigned int*)(vin + ib);
      SCAN_STEP(w0, blo(kA), blo(vA), Ap0, Aq0, Ao0)
      SCAN_STEP(w1, bhi(kA), bhi(vA), Ap1, Aq1, Ao1)
      SCAN_STEP(w0, blo(kB), blo(vB), Bp0, Bq0, Bo0)
      SCAN_STEP(w1, bhi(kB), bhi(vB), Bp1, Bq1, Bo1)
    }
  }
  ps[jA][2 * ci] = Ap0; qs[jA][2 * ci] = Aq0; os[jA][2 * ci] = Ao0;
  ps[jA][2 * ci + 1] = Ap1; qs[jA][2 * ci + 1] = Aq1; os[jA][2 * ci + 1] = Ao1;
  ps[jB][2 * ci] = Bp0; qs[jB][2 * ci] = Bq0; os[jB][2 * ci] = Bo0;
  ps[jB][2 * ci + 1] = Bp1; qs[jB][2 * ci + 1] = Bq1; os[jB][2 * ci + 1] = Bo1;
  __syncthreads();

  // ---- phase 2: Kogge-Stone inclusive scan over 32 chunks (5 steps) ----
#pragma unroll
  for (int s = 1; s < NCH; s <<= 1) {
    float tAp0 = Ap0, tAq0 = Aq0, tAo0 = Ao0, tAp1 = Ap1, tAq1 = Aq1, tAo1 = Ao1;
    float tBp0 = Bp0, tBq0 = Bq0, tBo0 = Bo0, tBp1 = Bp1, tBq1 = Bq1, tBo1 = Bo1;
    if (jA >= s) {
      KS_COMBINE(w0, ps[jA - s][2 * ci], qs[jA - s][2 * ci], os[jA - s][2 * ci],
                 tAp0, tAq0, tAo0, s * CL)
      KS_COMBINE(w1, ps[jA - s][2 * ci + 1], qs[jA - s][2 * ci + 1], os[jA - s][2 * ci + 1],
                 tAp1, tAq1, tAo1, s * CL)
    }
    // jB = j+16 >= 16 >= s always
    KS_COMBINE(w0, ps[jB - s][2 * ci], qs[jB - s][2 * ci], os[jB - s][2 * ci],
               tBp0, tBq0, tBo0, s * CL)
    KS_COMBINE(w1, ps[jB - s][2 * ci + 1], qs[jB - s][2 * ci + 1], os[jB - s][2 * ci + 1],
               tBp1, tBq1, tBo1, s * CL)
    __syncthreads();
    Ap0 = tAp0; Aq0 = tAq0; Ao0 = tAo0; Ap1 = tAp1; Aq1 = tAq1; Ao1 = tAo1;
    Bp0 = tBp0; Bq0 = tBq0; Bo0 = tBo0; Bp1 = tBp1; Bq1 = tBq1; Bo1 = tBo1;
    ps[jA][2 * ci] = Ap0; qs[jA][2 * ci] = Aq0; os[jA][2 * ci] = Ao0;
    ps[jA][2 * ci + 1] = Ap1; qs[jA][2 * ci + 1] = Aq1; os[jA][2 * ci + 1] = Ao1;
    ps[jB][2 * ci] = Bp0; qs[jB][2 * ci] = Bq0; os[jB][2 * ci] = Bo0;
    ps[jB][2 * ci + 1] = Bp1; qs[jB][2 * ci + 1] = Bq1; os[jB][2 * ci + 1] = Bo1;
    __syncthreads();
  }

  // ---- phase 3: re-scan both chunks with exclusive prefixes (2-way ILP) ----
  float pA0 = 0.f, qA0 = 0.f, oA0 = -1e38f, pA1 = 0.f, qA1 = 0.f, oA1 = -1e38f;
  if (j > 0) {
    pA0 = ps[jA - 1][2 * ci]; qA0 = qs[jA - 1][2 * ci]; oA0 = os[jA - 1][2 * ci];
    pA1 = ps[jA - 1][2 * ci + 1]; qA1 = qs[jA - 1][2 * ci + 1]; oA1 = os[jA - 1][2 * ci + 1];
  }
  float pB0 = ps[jB - 1][2 * ci], qB0 = qs[jB - 1][2 * ci], oB0 = os[jB - 1][2 * ci];
  float pB1 = ps[jB - 1][2 * ci + 1], qB1 = qs[jB - 1][2 * ci + 1], oB1 = os[jB - 1][2 * ci + 1];

  {
    size_t ia = baseA, ib = baseB;
#pragma unroll 4
    for (int t = 0; t < CL; ++t, ia += C_, ib += C_) {
      const unsigned int kA = *(const unsigned int*)(kin + ia);
      const unsigned int vA = *(const unsigned int*)(vin + ia);
      const unsigned int rA = *(const unsigned int*)(rin + ia);
      const unsigned int kB = *(const unsigned int*)(kin + ib);
      const unsigned int vB = *(const unsigned int*)(vin + ib);
      const unsigned int rB = *(const unsigned int*)(rin + ib);
      float y0, y1;
      Y_STEP(w0, u0, blo(kA), blo(vA), blo(rA), pA0, qA0, oA0, y0)
      Y_STEP(w1, u1, bhi(kA), bhi(vA), bhi(rA), pA1, qA1, oA1, y1)
      const unsigned int zoA = (unsigned int)f2bf(y0) | (((unsigned int)f2bf(y1)) << 16);
      Y_STEP(w0, u0, blo(kB), blo(vB), blo(rB), pB0, qB0, oB0, y0)
      Y_STEP(w1, u1, bhi(kB), bhi(vB), bhi(rB), pB1, qB1, oB1, y1)
      const unsigned int zoB = (unsigned int)f2bf(y0) | (((unsigned int)f2bf(y1)) << 16);
      *(unsigned int*)(z + ia) = zoA;
      *(unsigned int*)(z + ib) = zoB;
    }
  }
}

// ---------------------------------------------------------------------------
extern "C" void kernel_launch(void* const* d_in, const int* in_sizes, int n_in,
                              void* d_out, int out_size, void* d_ws,
                              size_t ws_size, hipStream_t stream) {
  const float* x   = (const float*)d_in[0];
  const float* td  = (const float*)d_in[1];
  const float* tf  = (const float*)d_in[2];
  const float* tmk = (const float*)d_in[3];
  const float* tmv = (const float*)d_in[4];
  const float* tmr = (const float*)d_in[5];
  const float* Wk  = (const float*)d_in[6];
  const float* Wv  = (const float*)d_in[7];
  const float* Wr  = (const float*)d_in[8];
  const float* Wo  = (const float*)d_in[9];

  const size_t nW = (size_t)C_ * C_;
  const size_t nM = (size_t)M_ * C_;

  // ws (244.5 MiB): [wbk wbv wbr wbo][xk][xv][xr][kbuf][vbuf]  (all bf16)
  // rbuf lives in d_out (bf16; consumed by wkv before final GEMM overwrites)
  // z overlays xv (dead after gemm_v)
  unsigned short* wbk  = (unsigned short*)d_ws;
  unsigned short* wbv  = wbk + nW;
  unsigned short* wbr  = wbv + nW;
  unsigned short* wbo  = wbr + nW;
  unsigned short* xk   = wbo + nW;
  unsigned short* xv   = xk + nM;
  unsigned short* xr   = xv + nM;
  unsigned short* kbuf = xr + nM;
  unsigned short* vbuf = kbuf + nM;
  unsigned short* rbuf = (unsigned short*)d_out;
  unsigned short* zb   = xv;   // reuse

  prep<<<WBLK + MBLK, 256, 0, stream>>>(x, tmk, tmv, tmr, Wk, Wv, Wr, Wo,
                                        wbk, wbv, wbr, wbo, xk, xv, xr);

  gemm8<1><<<GNB, 256, 0, stream>>>(xk, wbk, kbuf);   // xk dies
  gemm8<1><<<GNB, 256, 0, stream>>>(xv, wbv, vbuf);   // xv dies
  gemm8<1><<<GNB, 256, 0, stream>>>(xr, wbr, rbuf);   // -> d_out (bf16)

  wkv_scan<<<B_ * (C_ / 64), 512, 0, stream>>>(kbuf, vbuf, rbuf, td, tf, zb);

  gemm8<0><<<GNB, 256, 0, stream>>>(zb, wbo, d_out);  // f32 out
}